// Round 4
// baseline (383.029 us; speedup 1.0000x reference)
//
#include <hip/hip_runtime.h>
#include <math.h>

#define B_   4
#define S_   2048
#define E_   256
#define H_   8
#define DK_  32
#define NROWS (B_*S_)   // 8192

typedef unsigned short ushort_t;
typedef __attribute__((ext_vector_type(8))) short  bf16x8;
typedef __attribute__((ext_vector_type(4))) float  f32x4;
typedef __attribute__((ext_vector_type(4))) unsigned short us4;

// log2(e) and 1/sqrt(32)*log2(e): scores are produced in log2 domain
#define LOG2E 1.4426950408889634f
#define QSCALE (0.17677669529663687f * 1.4426950408889634f)

__device__ __forceinline__ ushort_t bf16_rne(float x)
{
    unsigned int u = __float_as_uint(x);
    unsigned int r = u + 0x7FFFu + ((u >> 16) & 1u);
    return (ushort_t)(r >> 16);
}
__device__ __forceinline__ float bf16_to_f(ushort_t h)
{
    return __uint_as_float(((unsigned int)h) << 16);
}

// ---------------------------------------------------------------------------
// GEMM: acc[n,m] = sum_k X[n,k]*W[m,k] + bias[m]
// mode 0: fp32, Y[n*E+m]                      (final projection)
// mode 1: Q   -> hi/lo bf16 head-split [bh][s][dk], scaled by QSCALE
// mode 2: K   -> hi/lo bf16 head-split [bh][s][dk]
// mode 3: V   -> bf16 TRANSPOSED [bh][d][S]
// ---------------------------------------------------------------------------
__global__ __launch_bounds__(256)
void gemm64(const float* __restrict__ X, const float* __restrict__ W,
            const float* __restrict__ bias, float* __restrict__ Yf,
            ushort_t* __restrict__ Y1, ushort_t* __restrict__ Y2,
            float scale, int mode)
{
    __shared__ float sA[16][64];   // [k][n]
    __shared__ float sB[16][64];   // [k][m]
    const int tid = threadIdx.x;
    const int tx = tid & 15, ty = tid >> 4;
    const int n0 = blockIdx.y * 64, m0 = blockIdx.x * 64;
    const int lr = tid >> 2;
    const int lc = (tid & 3) * 4;

    float acc[4][4] = {};
    for (int k0 = 0; k0 < E_; k0 += 16) {
        const float4 ax = *(const float4*)(X + (size_t)(n0 + lr) * E_ + k0 + lc);
        const float4 wx = *(const float4*)(W + (size_t)(m0 + lr) * E_ + k0 + lc);
        __syncthreads();
        sA[lc+0][lr] = ax.x; sA[lc+1][lr] = ax.y; sA[lc+2][lr] = ax.z; sA[lc+3][lr] = ax.w;
        sB[lc+0][lr] = wx.x; sB[lc+1][lr] = wx.y; sB[lc+2][lr] = wx.z; sB[lc+3][lr] = wx.w;
        __syncthreads();
        #pragma unroll
        for (int kk = 0; kk < 16; kk++) {
            const float4 av = *(const float4*)&sA[kk][ty * 4];
            const float4 bv = *(const float4*)&sB[kk][tx * 4];
            const float ar[4] = {av.x, av.y, av.z, av.w};
            const float br[4] = {bv.x, bv.y, bv.z, bv.w};
            #pragma unroll
            for (int i = 0; i < 4; i++)
                #pragma unroll
                for (int j = 0; j < 4; j++)
                    acc[i][j] = fmaf(ar[i], br[j], acc[i][j]);
        }
    }

    const float4 bb = *(const float4*)(bias + m0 + tx * 4);
    const float badd[4] = {bb.x, bb.y, bb.z, bb.w};

    if (mode == 0) {
        #pragma unroll
        for (int i = 0; i < 4; i++) {
            const int n = n0 + ty * 4 + i;
            float4 o = {acc[i][0]+badd[0], acc[i][1]+badd[1], acc[i][2]+badd[2], acc[i][3]+badd[3]};
            *(float4*)(Yf + (size_t)n * E_ + m0 + tx * 4) = o;
        }
    } else if (mode <= 2) {
        const int m  = m0 + tx * 4;          // 4 cols never cross a 32-wide head
        const int hh = m >> 5, d0 = m & 31;
        #pragma unroll
        for (int i = 0; i < 4; i++) {
            const int n  = n0 + ty * 4 + i;
            const int bI = n >> 11, sI = n & (S_ - 1);
            const size_t base = ((size_t)(bI * H_ + hh) * S_ + sI) * DK_ + d0;
            us4 h4, l4;
            #pragma unroll
            for (int jm = 0; jm < 4; jm++) {
                const float x = (acc[i][jm] + badd[jm]) * scale;
                const ushort_t hb = bf16_rne(x);
                h4[jm] = hb;
                l4[jm] = bf16_rne(x - bf16_to_f(hb));
            }
            *(us4*)&Y1[base] = h4;
            *(us4*)&Y2[base] = l4;
        }
    } else {   // V transposed: [bh][d][S]
        const int n  = n0 + ty * 4;          // 4 consecutive s, same b
        const int bI = n >> 11, sI = n & (S_ - 1);
        #pragma unroll
        for (int jm = 0; jm < 4; jm++) {
            const int m  = m0 + tx * 4 + jm;
            const int hh = m >> 5, d = m & 31;
            us4 col;
            #pragma unroll
            for (int i = 0; i < 4; i++)
                col[i] = bf16_rne(acc[i][jm] + badd[jm]);
            *(us4*)&Y1[((size_t)(bI * H_ + hh) * DK_ + d) * S_ + sI] = col;
        }
    }
}

// ---------------------------------------------------------------------------
// Flash decay attention — ONE WAVE PER BLOCK, fully independent.
// Block = (bh, q-tile tq, 16-row strip w). K/V fragments read straight from
// global (pre-converted bf16, 16B/lane coalesced). No __syncthreads anywhere.
// LDS only for the wave-private P C-layout -> A-layout round trip.
// Scores in log2 domain (log2e folded into Q scale): all exps are raw exp2f.
// MFMA 16x16x32 bf16; QK^T = 3-term hi/lo split (~fp32 accuracy).
//   A-frag: A[m=lane&15][k=(lane>>4)*8+j]
//   B-frag: B[k=(lane>>4)*8+j][n=lane&15]
//   C/D   : col=lane&15, row=(lane>>4)*4+reg
// ---------------------------------------------------------------------------
#define VPAD 72   // ushort stride for P rows (144 B, 16B-aligned)

__global__ __launch_bounds__(64)
void attn_flash(const ushort_t* __restrict__ Qhi, const ushort_t* __restrict__ Qlo,
                const ushort_t* __restrict__ Khi, const ushort_t* __restrict__ Klo,
                const ushort_t* __restrict__ Vt,  const float* __restrict__ gammas,
                float* __restrict__ Out)
{
    __shared__ __align__(16) ushort_t sP[16 * VPAD];   // wave-private

    const int lane = threadIdx.x;
    const int lr   = lane & 15;
    const int lq   = lane >> 4;
    const int unit = blockIdx.x >> 7;          // 0..31, longest first
    const int tq   = 31 - unit;
    const int sub  = blockIdx.x & 127;
    const int bh   = sub & 31;
    const int w    = sub >> 5;                 // 16-row strip within 64-row group
    const int h    = bh & 7;
    const int b    = bh >> 3;
    const int i0   = tq * 64 + w * 16;

    const ushort_t* Kbh = Khi + (size_t)bh * S_ * DK_;
    const ushort_t* Kbl = Klo + (size_t)bh * S_ * DK_;
    const ushort_t* Vbh = Vt  + (size_t)bh * DK_ * S_;

    const float g     = gammas[h];
    const float gamma = -((g > 20.f) ? g : log1pf(__expf(g)));
    const float gl2   = gamma * LOG2E;

    // Q fragments (already scaled by log2e/sqrt(dk), hi/lo bf16)
    const size_t qoff = ((size_t)bh * S_ + i0 + lr) * DK_ + lq * 8;
    const bf16x8 qhi = *(const bf16x8*)(Qhi + qoff);
    const bf16x8 qlo = *(const bf16x8*)(Qlo + qoff);

    // ======================= PASS A: m1', Z' ==============================
    float m1v[4], z1v[4];
    #pragma unroll
    for (int r = 0; r < 4; r++) { m1v[r] = -3.0e38f; z1v[r] = 0.f; }

    for (int jt = 0; jt <= tq; jt++) {
        const int j0 = jt * 64;
        f32x4 acc[4];
        #pragma unroll
        for (int t = 0; t < 4; t++) {
            const size_t ko = (size_t)(j0 + t * 16 + lr) * DK_ + lq * 8;
            const bf16x8 khi = *(const bf16x8*)(Kbh + ko);
            const bf16x8 klo = *(const bf16x8*)(Kbl + ko);
            f32x4 a = {0.f, 0.f, 0.f, 0.f};
            a = __builtin_amdgcn_mfma_f32_16x16x32_bf16(qlo, khi, a, 0, 0, 0);
            a = __builtin_amdgcn_mfma_f32_16x16x32_bf16(qhi, klo, a, 0, 0, 0);
            a = __builtin_amdgcn_mfma_f32_16x16x32_bf16(qhi, khi, a, 0, 0, 0);
            acc[t] = a;
        }
        if (jt == tq) {
            #pragma unroll
            for (int t = 0; t < 4; t++)
                #pragma unroll
                for (int r = 0; r < 4; r++) {
                    const int irow = i0 + lq * 4 + r;
                    const int j    = j0 + t * 16 + lr;
                    if (j > irow) acc[t][r] = -3.0e38f;
                }
        }
        #pragma unroll
        for (int r = 0; r < 4; r++) {
            float tm = fmaxf(fmaxf(acc[0][r], acc[1][r]), fmaxf(acc[2][r], acc[3][r]));
            #pragma unroll
            for (int off = 1; off < 16; off <<= 1)
                tm = fmaxf(tm, __shfl_xor(tm, off));
            const float mnew = fmaxf(m1v[r], tm);
            const float al   = exp2f(m1v[r] - mnew);
            float rs = 0.f;
            #pragma unroll
            for (int t = 0; t < 4; t++) rs += exp2f(acc[t][r] - mnew);
            #pragma unroll
            for (int off = 1; off < 16; off <<= 1)
                rs += __shfl_xor(rs, off);
            z1v[r] = z1v[r] * al + rs;
            m1v[r] = mnew;
        }
    }
    float invZ[4];
    #pragma unroll
    for (int r = 0; r < 4; r++) invZ[r] = 1.0f / z1v[r];

    // ======================= PASS B ======================================
    float m2v[4], z2v[4], carry[4];
    f32x4 O0 = {0.f,0.f,0.f,0.f}, O1 = {0.f,0.f,0.f,0.f};
    #pragma unroll
    for (int r = 0; r < 4; r++) { m2v[r] = -3.0e38f; z2v[r] = 0.f; carry[r] = 0.f; }

    for (int jt = 0; jt <= tq; jt++) {
        const int j0 = jt * 64;
        // scores (identical to pass A for Z-consistency)
        f32x4 acc[4];
        #pragma unroll
        for (int t = 0; t < 4; t++) {
            const size_t ko = (size_t)(j0 + t * 16 + lr) * DK_ + lq * 8;
            const bf16x8 khi = *(const bf16x8*)(Kbh + ko);
            const bf16x8 klo = *(const bf16x8*)(Kbl + ko);
            f32x4 a = {0.f, 0.f, 0.f, 0.f};
            a = __builtin_amdgcn_mfma_f32_16x16x32_bf16(qlo, khi, a, 0, 0, 0);
            a = __builtin_amdgcn_mfma_f32_16x16x32_bf16(qhi, klo, a, 0, 0, 0);
            a = __builtin_amdgcn_mfma_f32_16x16x32_bf16(qhi, khi, a, 0, 0, 0);
            acc[t] = a;
        }
        if (jt == tq) {
            #pragma unroll
            for (int t = 0; t < 4; t++)
                #pragma unroll
                for (int r = 0; r < 4; r++) {
                    const int irow = i0 + lq * 4 + r;
                    const int j    = j0 + t * 16 + lr;
                    if (j > irow) acc[t][r] = -3.0e38f;
                }
        }

        // p1, prefix-scan cumsum, decay -> s2' (in place)
        #pragma unroll
        for (int r = 0; r < 4; r++) {
            const int irow = i0 + lq * 4 + r;
            float base = carry[r];
            #pragma unroll
            for (int t = 0; t < 4; t++) {
                const int j = j0 + t * 16 + lr;
                float v = exp2f(acc[t][r] - m1v[r]) * invZ[r];    // p1
                #pragma unroll
                for (int off = 1; off < 16; off <<= 1) {
                    const float x = __shfl_up(v, off);
                    if (lr >= off) v += x;
                }
                const float tot = __shfl(v, lane | 15);
                const float cum = v + base;
                base += tot;
                const float rest = fmaxf(1.0f - cum, 0.f);
                const float posf = (float)(irow - j);
                const float dist = sqrtf(fmaxf(rest * posf, 0.f));
                const float eff  = fmaxf(exp2f(gl2 * dist), 1e-5f);  // <=1 always
                acc[t][r] = acc[t][r] * eff;                          // s2' (log2 dom)
            }
            carry[r] = base;
        }

        // online softmax-2 + P (bf16) into wave-private LDS (A-layout rows)
        #pragma unroll
        for (int r = 0; r < 4; r++) {
            float tm = fmaxf(fmaxf(acc[0][r], acc[1][r]), fmaxf(acc[2][r], acc[3][r]));
            #pragma unroll
            for (int off = 1; off < 16; off <<= 1)
                tm = fmaxf(tm, __shfl_xor(tm, off));
            const float mnew = fmaxf(m2v[r], tm);
            const float al   = exp2f(m2v[r] - mnew);
            O0[r] *= al; O1[r] *= al;
            float p2[4], rs = 0.f;
            #pragma unroll
            for (int t = 0; t < 4; t++) { p2[t] = exp2f(acc[t][r] - mnew); rs += p2[t]; }
            #pragma unroll
            for (int off = 1; off < 16; off <<= 1)
                rs += __shfl_xor(rs, off);
            z2v[r] = z2v[r] * al + rs;
            m2v[r] = mnew;
            const int m = lq * 4 + r;
            #pragma unroll
            for (int t = 0; t < 4; t++)
                sP[m * VPAD + t * 16 + lr] = bf16_rne(p2[t]);
        }

        // PV: P (A-frag from LDS) x Vt (B-frag from GLOBAL, pre-transposed)
        #pragma unroll
        for (int kc = 0; kc < 2; kc++) {
            const bf16x8 pa = *(const bf16x8*)&sP[lr * VPAD + kc * 32 + lq * 8];
            const bf16x8 v0 = *(const bf16x8*)(Vbh + (size_t)(0  + lr) * S_ + j0 + kc * 32 + lq * 8);
            const bf16x8 v1 = *(const bf16x8*)(Vbh + (size_t)(16 + lr) * S_ + j0 + kc * 32 + lq * 8);
            O0 = __builtin_amdgcn_mfma_f32_16x16x32_bf16(pa, v0, O0, 0, 0, 0);
            O1 = __builtin_amdgcn_mfma_f32_16x16x32_bf16(pa, v1, O1, 0, 0, 0);
        }
    }

    // ---- epilogue: normalize, write concat [B,S,E] -----------------------
    #pragma unroll
    for (int r = 0; r < 4; r++) {
        const float inv  = 1.0f / z2v[r];
        const int   irow = i0 + lq * 4 + r;
        float* orow = Out + ((size_t)(b * S_ + irow)) * E_ + h * DK_;
        orow[lr]      = O0[r] * inv;
        orow[16 + lr] = O1[r] * inv;
    }
}

// ---------------------------------------------------------------------------
extern "C" void kernel_launch(void* const* d_in, const int* in_sizes, int n_in,
                              void* d_out, int out_size, void* d_ws, size_t ws_size,
                              hipStream_t stream)
{
    const float* q      = (const float*)d_in[0];
    const float* k      = (const float*)d_in[1];
    const float* v      = (const float*)d_in[2];
    // d_in[3] = causal mask (analytic; unused)
    const float* Wq     = (const float*)d_in[4];
    const float* bq     = (const float*)d_in[5];
    const float* Wk     = (const float*)d_in[6];
    const float* bk     = (const float*)d_in[7];
    const float* Wv     = (const float*)d_in[8];
    const float* bv     = (const float*)d_in[9];
    const float* Wo     = (const float*)d_in[10];
    const float* bo     = (const float*)d_in[11];
    const float* gammas = (const float*)d_in[12];
    float* out = (float*)d_out;

    const size_t headN = (size_t)B_ * H_ * S_ * DK_;   // 2M elements
    ushort_t* qhi = (ushort_t*)d_ws;
    ushort_t* qlo = qhi + headN;
    ushort_t* khi = qlo + headN;
    ushort_t* klo = khi + headN;
    ushort_t* vt  = klo + headN;
    float* concat = (float*)(vt + headN);              // [B,S,E] fp32

    dim3 blk(256);
    dim3 grd(E_ / 64, NROWS / 64);
    gemm64<<<grd, blk, 0, stream>>>(q, Wq, bq, nullptr, qhi, qlo, QSCALE, 1);
    gemm64<<<grd, blk, 0, stream>>>(k, Wk, bk, nullptr, khi, klo, 1.0f,   2);
    gemm64<<<grd, blk, 0, stream>>>(v, Wv, bv, nullptr, vt,  nullptr, 1.0f, 3);

    attn_flash<<<32 * 32 * 4, 64, 0, stream>>>(qhi, qlo, khi, klo, vt, gammas, concat);

    gemm64<<<grd, blk, 0, stream>>>(concat, Wo, bo, out, nullptr, nullptr, 1.0f, 0);
}

// Round 5
// 312.919 us; speedup vs baseline: 1.2241x; 1.2241x over previous
//
#include <hip/hip_runtime.h>
#include <math.h>

#define B_   4
#define S_   2048
#define E_   256
#define H_   8
#define DK_  32
#define NROWS (B_*S_)   // 8192

typedef unsigned short ushort_t;
typedef __attribute__((ext_vector_type(8))) short  bf16x8;
typedef __attribute__((ext_vector_type(4))) float  f32x4;
typedef __attribute__((ext_vector_type(4))) unsigned short us4;

#define LOG2E 1.4426950408889634f
#define QSCALE (0.17677669529663687f * 1.4426950408889634f)   // 1/sqrt(32) * log2(e)

#if __has_builtin(__builtin_amdgcn_exp2f)
#define EXP2F(x) __builtin_amdgcn_exp2f(x)
#else
#define EXP2F(x) exp2f(x)
#endif
#if __has_builtin(__builtin_amdgcn_sqrtf)
#define SQRTF(x) __builtin_amdgcn_sqrtf(x)
#else
#define SQRTF(x) sqrtf(x)
#endif
#if __has_builtin(__builtin_amdgcn_rcpf)
#define RCPF(x) __builtin_amdgcn_rcpf(x)
#else
#define RCPF(x) (1.0f/(x))
#endif

__device__ __forceinline__ ushort_t bf16_rne(float x)
{
    unsigned int u = __float_as_uint(x);
    unsigned int r = u + 0x7FFFu + ((u >> 16) & 1u);
    return (ushort_t)(r >> 16);
}
__device__ __forceinline__ float bf16_to_f(ushort_t h)
{
    return __uint_as_float(((unsigned int)h) << 16);
}

// 16-lane (DPP-row) inclusive prefix scan: 4 full-rate VALU adds, no LDS.
__device__ __forceinline__ float scan16(float x)
{
    x += __int_as_float(__builtin_amdgcn_update_dpp(0, __float_as_int(x), 0x111, 0xF, 0xF, true)); // row_shr:1
    x += __int_as_float(__builtin_amdgcn_update_dpp(0, __float_as_int(x), 0x112, 0xF, 0xF, true)); // row_shr:2
    x += __int_as_float(__builtin_amdgcn_update_dpp(0, __float_as_int(x), 0x114, 0xF, 0xF, true)); // row_shr:4
    x += __int_as_float(__builtin_amdgcn_update_dpp(0, __float_as_int(x), 0x118, 0xF, 0xF, true)); // row_shr:8
    return x;
}
// broadcast lane 15 of each 16-lane group: ds_swizzle BitMode and=0x10,or=0xF
__device__ __forceinline__ float bcast15(float x)
{
    return __int_as_float(__builtin_amdgcn_ds_swizzle(__float_as_int(x), 0x1F0));
}

// ---------------------------------------------------------------------------
// fp32 -> hi/lo bf16 conversion kernels
// ---------------------------------------------------------------------------
__global__ __launch_bounds__(256)
void conv_x3(const float* __restrict__ q, const float* __restrict__ k,
             const float* __restrict__ v,
             ushort_t* __restrict__ qh, ushort_t* __restrict__ ql,
             ushort_t* __restrict__ kh, ushort_t* __restrict__ kl,
             ushort_t* __restrict__ vh, ushort_t* __restrict__ vl)
{
    const int z = blockIdx.y;
    const float* src = (z == 0) ? q : (z == 1) ? k : v;
    ushort_t* dh = (z == 0) ? qh : (z == 1) ? kh : vh;
    ushort_t* dl = (z == 0) ? ql : (z == 1) ? kl : vl;
    const size_t i = ((size_t)blockIdx.x * 256 + threadIdx.x) * 4;
    const float4 x = *(const float4*)(src + i);
    const float xs[4] = {x.x, x.y, x.z, x.w};
    us4 hv, lv;
    #pragma unroll
    for (int c = 0; c < 4; c++) {
        const ushort_t hb = bf16_rne(xs[c]);
        hv[c] = hb;
        lv[c] = bf16_rne(xs[c] - bf16_to_f(hb));
    }
    *(us4*)&dh[i] = hv;
    *(us4*)&dl[i] = lv;
}

__global__ __launch_bounds__(256)
void conv_w4(const float* __restrict__ w0, const float* __restrict__ w1,
             const float* __restrict__ w2, const float* __restrict__ w3,
             ushort_t* __restrict__ oh, ushort_t* __restrict__ ol)
{
    const int z = blockIdx.y;
    const float* src = (z == 0) ? w0 : (z == 1) ? w1 : (z == 2) ? w2 : w3;
    ushort_t* dh = oh + (size_t)z * E_ * E_;
    ushort_t* dl = ol + (size_t)z * E_ * E_;
    const size_t i = ((size_t)blockIdx.x * 256 + threadIdx.x) * 4;
    const float4 x = *(const float4*)(src + i);
    const float xs[4] = {x.x, x.y, x.z, x.w};
    us4 hv, lv;
    #pragma unroll
    for (int c = 0; c < 4; c++) {
        const ushort_t hb = bf16_rne(xs[c]);
        hv[c] = hb;
        lv[c] = bf16_rne(xs[c] - bf16_to_f(hb));
    }
    *(us4*)&dh[i] = hv;
    *(us4*)&dl[i] = lv;
}

// ---------------------------------------------------------------------------
// 3-term hi/lo bf16 MFMA GEMM: Y[n,m] = sum_k X[n,k]*W[m,k] + bias[m]
// Both A (X rows) and B (W rows) fragments are K-major -> direct global loads,
// no LDS. Block = 256 thr = 4 waves; wave owns 16 rows x 64 cols.
// mode 0: fp32 out Y[n*E+m]
// mode 1: hi/lo bf16 head-split [bh][s][dk], scaled  (Q: scale=QSCALE, K: 1)
// mode 2: bf16 transposed [bh][d][S]                 (V)
// ---------------------------------------------------------------------------
__global__ __launch_bounds__(256)
void gemm_mfma(const ushort_t* __restrict__ Xhi, const ushort_t* __restrict__ Xlo,
               const ushort_t* __restrict__ Whi, const ushort_t* __restrict__ Wlo,
               const float* __restrict__ bias, int mode, float scale,
               ushort_t* __restrict__ Y1, ushort_t* __restrict__ Y2,
               float* __restrict__ Yf)
{
    const int tid = threadIdx.x;
    const int lane = tid & 63, w = tid >> 6;
    const int lr = lane & 15, lq = lane >> 4;
    const int m0 = blockIdx.x * 64;
    const int n0 = blockIdx.y * 64 + w * 16;

    const size_t xrow = (size_t)(n0 + lr) * E_ + lq * 8;
    f32x4 acc[4] = {{0,0,0,0},{0,0,0,0},{0,0,0,0},{0,0,0,0}};

    for (int k0 = 0; k0 < E_; k0 += 32) {
        const bf16x8 ahi = *(const bf16x8*)(Xhi + xrow + k0);
        const bf16x8 alo = *(const bf16x8*)(Xlo + xrow + k0);
        #pragma unroll
        for (int t = 0; t < 4; t++) {
            const size_t wrow = (size_t)(m0 + t * 16 + lr) * E_ + k0 + lq * 8;
            const bf16x8 bhi = *(const bf16x8*)(Whi + wrow);
            const bf16x8 blo = *(const bf16x8*)(Wlo + wrow);
            acc[t] = __builtin_amdgcn_mfma_f32_16x16x32_bf16(alo, bhi, acc[t], 0, 0, 0);
            acc[t] = __builtin_amdgcn_mfma_f32_16x16x32_bf16(ahi, blo, acc[t], 0, 0, 0);
            acc[t] = __builtin_amdgcn_mfma_f32_16x16x32_bf16(ahi, bhi, acc[t], 0, 0, 0);
        }
    }

    #pragma unroll
    for (int t = 0; t < 4; t++) {
        const int col = m0 + t * 16 + lr;
        const float bt = bias[col];
        if (mode == 0) {
            #pragma unroll
            for (int reg = 0; reg < 4; reg++) {
                const int n = n0 + lq * 4 + reg;
                Yf[(size_t)n * E_ + col] = acc[t][reg] + bt;
            }
        } else if (mode == 1) {
            const int hh = col >> 5, d = col & 31;
            #pragma unroll
            for (int reg = 0; reg < 4; reg++) {
                const int n  = n0 + lq * 4 + reg;
                const int bI = n >> 11, sI = n & (S_ - 1);
                const size_t base = ((size_t)(bI * H_ + hh) * S_ + sI) * DK_ + d;
                const float y = (acc[t][reg] + bt) * scale;
                const ushort_t hb = bf16_rne(y);
                Y1[base] = hb;
                Y2[base] = bf16_rne(y - bf16_to_f(hb));
            }
        } else {  // mode 2: V transposed [bh][d][S]
            const int hh = col >> 5, d = col & 31;
            const int n  = n0 + lq * 4;
            const int bI = n >> 11, sI = n & (S_ - 1);
            us4 c;
            #pragma unroll
            for (int reg = 0; reg < 4; reg++)
                c[reg] = bf16_rne(acc[t][reg] + bt);
            *(us4*)&Y1[((size_t)(bI * H_ + hh) * DK_ + d) * S_ + sI] = c;
        }
    }
}

// ---------------------------------------------------------------------------
// Flash decay attention — one wave per block, no barriers.
// Fixed stabilizers (no online max/rescale):
//   Z1 = sum exp2(s'), p1 = exp2(s')/Z1  (log2-domain scores, safe range)
//   s2' = s' * eff, p2 = exp2(s2'), Z2 = sum p2    (s2' <= max(s',0) bounded)
// Prefix scan via DPP row_shr (full-rate VALU), chunk totals via ds_swizzle.
// 2-tile unrolled K-loop for ILP; phantom tile (fully masked) pads odd counts.
// Output written directly as hi/lo bf16 concat for the O-projection.
// ---------------------------------------------------------------------------
#define VPAD 72   // ushort stride for P rows

__device__ __forceinline__ void score_tile(f32x4 (&a)[4],
    const ushort_t* __restrict__ Kbh, const ushort_t* __restrict__ Kbl,
    int j0, const bf16x8& qhi, const bf16x8& qlo, int lr, int lq,
    bool domask, int i0)
{
    #pragma unroll
    for (int t = 0; t < 4; t++) {
        const size_t ko = (size_t)(j0 + t * 16 + lr) * DK_ + lq * 8;
        const bf16x8 khi = *(const bf16x8*)(Kbh + ko);
        const bf16x8 klo = *(const bf16x8*)(Kbl + ko);
        f32x4 v = {0.f, 0.f, 0.f, 0.f};
        v = __builtin_amdgcn_mfma_f32_16x16x32_bf16(qlo, khi, v, 0, 0, 0);
        v = __builtin_amdgcn_mfma_f32_16x16x32_bf16(qhi, klo, v, 0, 0, 0);
        v = __builtin_amdgcn_mfma_f32_16x16x32_bf16(qhi, khi, v, 0, 0, 0);
        a[t] = v;
    }
    if (domask) {
        #pragma unroll
        for (int t = 0; t < 4; t++)
            #pragma unroll
            for (int r = 0; r < 4; r++) {
                const int irow = i0 + lq * 4 + r;
                const int j    = j0 + t * 16 + lr;
                if (j > irow) a[t][r] = -3.0e38f;
            }
    }
}

__global__ __launch_bounds__(64)
void attn_flash(const ushort_t* __restrict__ Qhi, const ushort_t* __restrict__ Qlo,
                const ushort_t* __restrict__ Khi, const ushort_t* __restrict__ Klo,
                const ushort_t* __restrict__ Vt,  const float* __restrict__ gammas,
                ushort_t* __restrict__ Chi, ushort_t* __restrict__ Clo)
{
    __shared__ __align__(16) ushort_t sP[2][16 * VPAD];

    const int lane = threadIdx.x;
    const int lr   = lane & 15;
    const int lq   = lane >> 4;
    const int unit = blockIdx.x >> 7;          // 0..31, longest first
    const int tq   = 31 - unit;
    const int sub  = blockIdx.x & 127;
    const int bh   = sub & 31;
    const int w    = sub >> 5;
    const int h    = bh & 7;
    const int b    = bh >> 3;
    const int i0   = tq * 64 + w * 16;

    const ushort_t* Kbh = Khi + (size_t)bh * S_ * DK_;
    const ushort_t* Kbl = Klo + (size_t)bh * S_ * DK_;
    const ushort_t* Vbh = Vt  + (size_t)bh * DK_ * S_;

    const float g   = gammas[h];
    const float gl2 = -((g > 20.f) ? g : log1pf(__expf(g))) * LOG2E;

    const size_t qoff = ((size_t)bh * S_ + i0 + lr) * DK_ + lq * 8;
    const bf16x8 qhi = *(const bf16x8*)(Qhi + qoff);
    const bf16x8 qlo = *(const bf16x8*)(Qlo + qoff);

    const int nt  = tq + 1;
    const int ntp = (nt + 1) & ~1;             // pad to even (phantom fully masked)

    // ===================== PASS A: Z1 (no stabilizer) =====================
    float z1a[4] = {0.f, 0.f, 0.f, 0.f};
    for (int jt = 0; jt < ntp; jt += 2) {
        f32x4 a0[4], a1[4];
        score_tile(a0, Kbh, Kbl, (jt + 0) * 64, qhi, qlo, lr, lq, jt + 0 >= tq, i0);
        score_tile(a1, Kbh, Kbl, (jt + 1) * 64, qhi, qlo, lr, lq, jt + 1 >= tq, i0);
        #pragma unroll
        for (int t = 0; t < 4; t++)
            #pragma unroll
            for (int r = 0; r < 4; r++)
                z1a[r] += EXP2F(a0[t][r]) + EXP2F(a1[t][r]);
    }
    float invZ[4];
    #pragma unroll
    for (int r = 0; r < 4; r++) {
        float v = z1a[r];
        v += __shfl_xor(v, 1); v += __shfl_xor(v, 2);
        v += __shfl_xor(v, 4); v += __shfl_xor(v, 8);
        invZ[r] = RCPF(v);
    }

    // ===================== PASS B =========================================
    float carry[4] = {0.f, 0.f, 0.f, 0.f};
    float z2a[4]   = {0.f, 0.f, 0.f, 0.f};
    f32x4 O0 = {0.f,0.f,0.f,0.f}, O1 = {0.f,0.f,0.f,0.f};

    for (int jt = 0; jt < ntp; jt += 2) {
        f32x4 acc[2][4];
        score_tile(acc[0], Kbh, Kbl, (jt + 0) * 64, qhi, qlo, lr, lq, jt + 0 >= tq, i0);
        score_tile(acc[1], Kbh, Kbl, (jt + 1) * 64, qhi, qlo, lr, lq, jt + 1 >= tq, i0);

        #pragma unroll
        for (int p = 0; p < 2; p++) {
            const int j0 = (jt + p) * 64;
            // e = exp2(s'), 16 independent DPP scans + chunk totals
            float sc[4][4], tot[4][4];           // [t][r]
            #pragma unroll
            for (int t = 0; t < 4; t++)
                #pragma unroll
                for (int r = 0; r < 4; r++) {
                    const float e = EXP2F(acc[p][t][r]);
                    const float s = scan16(e);
                    sc[t][r]  = s;
                    tot[t][r] = bcast15(s);
                }
            // serial carry combine (cheap adds), then independent decay chains
            #pragma unroll
            for (int r = 0; r < 4; r++) {
                float base = carry[r];
                #pragma unroll
                for (int t = 0; t < 4; t++) {
                    sc[t][r] += base;            // inclusive cumsum (raw)
                    base += tot[t][r];
                }
                carry[r] = base;
            }
            ushort_t* sPp = &sP[p][0];
            #pragma unroll
            for (int t = 0; t < 4; t++) {
                const int j = j0 + t * 16 + lr;
                #pragma unroll
                for (int r = 0; r < 4; r++) {
                    const int irow = i0 + lq * 4 + r;
                    const float rest = fmaxf(fmaf(-sc[t][r], invZ[r], 1.0f), 0.f);
                    const float posf = (float)(irow - j);
                    const float dist = SQRTF(fmaxf(rest * posf, 0.f));
                    const float eff  = fmaxf(EXP2F(gl2 * dist), 1e-5f);
                    const float p2   = EXP2F(acc[p][t][r] * eff);
                    z2a[r] += p2;
                    sPp[(lq * 4 + r) * VPAD + t * 16 + lr] = bf16_rne(p2);
                }
            }
        }

        // PV for both tiles (LDS round trip is wave-internal, no barrier)
        #pragma unroll
        for (int p = 0; p < 2; p++) {
            const int j0 = (jt + p) * 64;
            const ushort_t* sPp = &sP[p][0];
            #pragma unroll
            for (int kc = 0; kc < 2; kc++) {
                const bf16x8 pa = *(const bf16x8*)&sPp[lr * VPAD + kc * 32 + lq * 8];
                const bf16x8 v0 = *(const bf16x8*)(Vbh + (size_t)(0  + lr) * S_ + j0 + kc * 32 + lq * 8);
                const bf16x8 v1 = *(const bf16x8*)(Vbh + (size_t)(16 + lr) * S_ + j0 + kc * 32 + lq * 8);
                O0 = __builtin_amdgcn_mfma_f32_16x16x32_bf16(pa, v0, O0, 0, 0, 0);
                O1 = __builtin_amdgcn_mfma_f32_16x16x32_bf16(pa, v1, O1, 0, 0, 0);
            }
        }
    }

    // ---- epilogue: normalize, write concat as hi/lo bf16 -----------------
    float inv2[4];
    #pragma unroll
    for (int r = 0; r < 4; r++) {
        float v = z2a[r];
        v += __shfl_xor(v, 1); v += __shfl_xor(v, 2);
        v += __shfl_xor(v, 4); v += __shfl_xor(v, 8);
        inv2[r] = RCPF(v);
    }
    #pragma unroll
    for (int r = 0; r < 4; r++) {
        const int irow = i0 + lq * 4 + r;
        const size_t o = ((size_t)(b * S_ + irow)) * E_ + h * DK_;
        const float y0 = O0[r] * inv2[r];
        const float y1 = O1[r] * inv2[r];
        const ushort_t h0 = bf16_rne(y0);
        const ushort_t h1 = bf16_rne(y1);
        Chi[o + lr]      = h0;  Clo[o + lr]      = bf16_rne(y0 - bf16_to_f(h0));
        Chi[o + 16 + lr] = h1;  Clo[o + 16 + lr] = bf16_rne(y1 - bf16_to_f(h1));
    }
}

// ---------------------------------------------------------------------------
extern "C" void kernel_launch(void* const* d_in, const int* in_sizes, int n_in,
                              void* d_out, int out_size, void* d_ws, size_t ws_size,
                              hipStream_t stream)
{
    const float* q      = (const float*)d_in[0];
    const float* k      = (const float*)d_in[1];
    const float* v      = (const float*)d_in[2];
    // d_in[3] = causal mask (analytic; unused)
    const float* Wq     = (const float*)d_in[4];
    const float* bq     = (const float*)d_in[5];
    const float* Wk     = (const float*)d_in[6];
    const float* bk     = (const float*)d_in[7];
    const float* Wv     = (const float*)d_in[8];
    const float* bv     = (const float*)d_in[9];
    const float* Wo     = (const float*)d_in[10];
    const float* bo     = (const float*)d_in[11];
    const float* gammas = (const float*)d_in[12];
    float* out = (float*)d_out;

    const size_t N2 = (size_t)NROWS * E_;      // 2M elements
    ushort_t* p   = (ushort_t*)d_ws;
    ushort_t* qhi = p;            ushort_t* qlo = qhi + N2;
    ushort_t* khi = qlo + N2;     ushort_t* klo = khi + N2;
    ushort_t* vt  = klo + N2;
    ushort_t* xqh = vt  + N2;     ushort_t* xql = xqh + N2;
    ushort_t* xkh = xql + N2;     ushort_t* xkl = xkh + N2;
    ushort_t* xvh = xkl + N2;     ushort_t* xvl = xvh + N2;
    ushort_t* chi = xvl + N2;     ushort_t* clo = chi + N2;
    ushort_t* wh  = clo + N2;                  // 4 x E*E hi
    ushort_t* wl  = wh + 4 * (size_t)E_ * E_;  // 4 x E*E lo

    // input & weight conversions
    conv_x3<<<dim3(N2 / 1024, 3), 256, 0, stream>>>(q, k, v, xqh, xql, xkh, xkl, xvh, xvl);
    conv_w4<<<dim3(E_ * E_ / 1024, 4), 256, 0, stream>>>(Wq, Wk, Wv, Wo, wh, wl);

    const size_t WN = (size_t)E_ * E_;
    dim3 gblk(256);
    dim3 ggrd(E_ / 64, NROWS / 64);
    gemm_mfma<<<ggrd, gblk, 0, stream>>>(xqh, xql, wh + 0*WN, wl + 0*WN, bq, 1, QSCALE, qhi, qlo, nullptr);
    gemm_mfma<<<ggrd, gblk, 0, stream>>>(xkh, xkl, wh + 1*WN, wl + 1*WN, bk, 1, 1.0f,   khi, klo, nullptr);
    gemm_mfma<<<ggrd, gblk, 0, stream>>>(xvh, xvl, wh + 2*WN, wl + 2*WN, bv, 2, 1.0f,   vt,  nullptr, nullptr);

    attn_flash<<<32 * 32 * 4, 64, 0, stream>>>(qhi, qlo, khi, klo, vt, gammas, chi, clo);

    gemm_mfma<<<ggrd, gblk, 0, stream>>>(chi, clo, wh + 3*WN, wl + 3*WN, bo, 0, 1.0f, nullptr, nullptr, out);
}

// Round 6
// 244.161 us; speedup vs baseline: 1.5688x; 1.2816x over previous
//
#include <hip/hip_runtime.h>
#include <math.h>

#define B_   4
#define S_   2048
#define E_   256
#define H_   8
#define DK_  32
#define NROWS (B_*S_)   // 8192

typedef unsigned short ushort_t;
typedef __attribute__((ext_vector_type(8))) short  bf16x8;
typedef __attribute__((ext_vector_type(4))) float  f32x4;

#define LOG2E 1.4426950408889634f
#define QSCALE (0.17677669529663687f * 1.4426950408889634f)   // 1/sqrt(32) * log2(e)

#if __has_builtin(__builtin_amdgcn_exp2f)
#define EXP2F(x) __builtin_amdgcn_exp2f(x)
#else
#define EXP2F(x) exp2f(x)
#endif
#if __has_builtin(__builtin_amdgcn_sqrtf)
#define SQRTF(x) __builtin_amdgcn_sqrtf(x)
#else
#define SQRTF(x) sqrtf(x)
#endif
#if __has_builtin(__builtin_amdgcn_rcpf)
#define RCPF(x) __builtin_amdgcn_rcpf(x)
#else
#define RCPF(x) (1.0f/(x))
#endif

__device__ __forceinline__ ushort_t bf16_rne(float x)
{
    unsigned int u = __float_as_uint(x);
    unsigned int r = u + 0x7FFFu + ((u >> 16) & 1u);
    return (ushort_t)(r >> 16);
}
__device__ __forceinline__ float bf16_to_f(ushort_t h)
{
    return __uint_as_float(((unsigned int)h) << 16);
}

// 16-lane (DPP-row) inclusive prefix scan: 4 full-rate VALU adds.
__device__ __forceinline__ float scan16(float x)
{
    x += __int_as_float(__builtin_amdgcn_update_dpp(0, __float_as_int(x), 0x111, 0xF, 0xF, true));
    x += __int_as_float(__builtin_amdgcn_update_dpp(0, __float_as_int(x), 0x112, 0xF, 0xF, true));
    x += __int_as_float(__builtin_amdgcn_update_dpp(0, __float_as_int(x), 0x114, 0xF, 0xF, true));
    x += __int_as_float(__builtin_amdgcn_update_dpp(0, __float_as_int(x), 0x118, 0xF, 0xF, true));
    return x;
}
__device__ __forceinline__ float bcast15(float x)
{
    return __int_as_float(__builtin_amdgcn_ds_swizzle(__float_as_int(x), 0x1F0));
}

// ===========================================================================
// Fragment-swizzled layout: for a [rows][K] operand, the 512-element block
// (16 rows x 32 k) is contiguous; within a block, a wave's MFMA fragment load
// is exactly  base + block*512 + lane*8  (1 KB fully coalesced).
//   intra(n,k) = ((k>>3)&3)*128 + (n&15)*8 + (k&7)
// ===========================================================================

// ---------------------------------------------------------------------------
// conv: fp32 [rows][256] -> swizzled hi/lo bf16.  z<3: inputs q,k,v (8192
// rows); z>=3: weights (256 rows, only blockIdx.x<16 active).
// ---------------------------------------------------------------------------
__global__ __launch_bounds__(256)
void conv_all(const float* __restrict__ q, const float* __restrict__ k,
              const float* __restrict__ v,
              const float* __restrict__ Wq, const float* __restrict__ Wk,
              const float* __restrict__ Wv, const float* __restrict__ Wo,
              ushort_t* __restrict__ xh, ushort_t* __restrict__ xl,
              ushort_t* __restrict__ wh, ushort_t* __restrict__ wl)
{
    const int z = blockIdx.y;
    const float* src;
    ushort_t *dh, *dl;
    if (z < 3) {
        src = (z == 0) ? q : (z == 1) ? k : v;
        dh = xh + (size_t)z * (NROWS * E_);
        dl = xl + (size_t)z * (NROWS * E_);
    } else {
        if (blockIdx.x >= 16) return;
        src = (z == 3) ? Wq : (z == 4) ? Wk : (z == 5) ? Wv : Wo;
        dh = wh + (size_t)(z - 3) * (E_ * E_);
        dl = wl + (size_t)(z - 3) * (E_ * E_);
    }
    const int n0 = blockIdx.x * 16;
    const int lr = threadIdx.x & 15, kq = threadIdx.x >> 4;   // kq 0..15
    #pragma unroll
    for (int half = 0; half < 2; half++) {
        const int kk = kq * 8 + half * 128;
        const float* s = src + (size_t)(n0 + lr) * E_ + kk;
        const float4 a = *(const float4*)s;
        const float4 b = *(const float4*)(s + 4);
        const float xs[8] = {a.x, a.y, a.z, a.w, b.x, b.y, b.z, b.w};
        bf16x8 hv, lv;
        #pragma unroll
        for (int e = 0; e < 8; e++) {
            const ushort_t hb = bf16_rne(xs[e]);
            hv[e] = (short)hb;
            lv[e] = (short)bf16_rne(xs[e] - bf16_to_f(hb));
        }
        const size_t o = ((size_t)blockIdx.x * 8 + (kk >> 5)) * 512
                       + ((kk >> 3) & 3) * 128 + lr * 8;
        *(bf16x8*)&dh[o] = hv;
        *(bf16x8*)&dl[o] = lv;
    }
}

// ---------------------------------------------------------------------------
// Direct swizzled MFMA GEMM (no LDS): Y[n,m] = sum_k X[n,k] W[m,k] + b[m].
// One wave per block: 16 n-rows x 64 m-cols, K=256 (8 chunks of 32).
// All fragment loads are base + block*512 + lane*8 (1 KB coalesced).
// mode 0: fp32 out [n][E]    mode 1: Q/K attn layout hi/lo (scaled)
// mode 2: V attn B-frag layout (bf16)
// ---------------------------------------------------------------------------
__global__ __launch_bounds__(64)
void gemm_frag(const ushort_t* __restrict__ Xh, const ushort_t* __restrict__ Xl,
               const ushort_t* __restrict__ Wh, const ushort_t* __restrict__ Wl,
               const float* __restrict__ bias, int mode, float scale,
               ushort_t* __restrict__ Y1, ushort_t* __restrict__ Y2,
               float* __restrict__ Yf)
{
    const int lane = threadIdx.x;
    const int lr = lane & 15, lq = lane >> 4;
    const int mb = blockIdx.x;                 // m-block: 4 m-tiles
    const int nstrip = blockIdx.y;             // 16 n-rows
    const size_t abase = (size_t)nstrip * 4096 + lane * 8;

    f32x4 acc[4] = {{0,0,0,0},{0,0,0,0},{0,0,0,0},{0,0,0,0}};

    #pragma unroll 2
    for (int kc = 0; kc < 8; kc++) {
        const bf16x8 ahi = *(const bf16x8*)(Xh + abase + kc * 512);
        const bf16x8 alo = *(const bf16x8*)(Xl + abase + kc * 512);
        #pragma unroll
        for (int t = 0; t < 4; t++) {
            const size_t wb = ((size_t)(mb * 4 + t) * 8 + kc) * 512 + lane * 8;
            const bf16x8 bhi = *(const bf16x8*)(Wh + wb);
            const bf16x8 blo = *(const bf16x8*)(Wl + wb);
            acc[t] = __builtin_amdgcn_mfma_f32_16x16x32_bf16(alo, bhi, acc[t], 0, 0, 0);
            acc[t] = __builtin_amdgcn_mfma_f32_16x16x32_bf16(ahi, blo, acc[t], 0, 0, 0);
            acc[t] = __builtin_amdgcn_mfma_f32_16x16x32_bf16(ahi, bhi, acc[t], 0, 0, 0);
        }
    }

    #pragma unroll
    for (int t = 0; t < 4; t++) {
        const int col = mb * 64 + t * 16 + lr;
        const float bt = bias[col];
        if (mode == 0) {
            #pragma unroll
            for (int reg = 0; reg < 4; reg++) {
                const int n = nstrip * 16 + lq * 4 + reg;
                Yf[(size_t)n * E_ + col] = acc[t][reg] + bt;
            }
        } else if (mode == 1) {                // Q/K -> attn A/B-frag layout
            const int h = col >> 5, d = col & 31;
            #pragma unroll
            for (int reg = 0; reg < 4; reg++) {
                const int n  = nstrip * 16 + lq * 4 + reg;
                const int bI = n >> 11, sI = n & (S_ - 1);
                const size_t o = (size_t)(bI * H_ + h) * (S_ * DK_)
                               + (size_t)(sI >> 4) * 512
                               + ((d >> 3) & 3) * 128 + (sI & 15) * 8 + (d & 7);
                const float y = (acc[t][reg] + bt) * scale;
                const ushort_t hb = bf16_rne(y);
                Y1[o] = hb;
                Y2[o] = bf16_rne(y - bf16_to_f(hb));
            }
        } else {                               // V -> attn B-frag layout
            const int h = col >> 5, d = col & 31;
            #pragma unroll
            for (int reg = 0; reg < 4; reg++) {
                const int n  = nstrip * 16 + lq * 4 + reg;
                const int bI = n >> 11, sI = n & (S_ - 1);
                const size_t o = (size_t)(bI * H_ + h) * (S_ * DK_)
                               + (size_t)((sI >> 5) * 2 + (d >> 4)) * 512
                               + ((sI >> 3) & 3) * 128 + (d & 15) * 8 + (sI & 7);
                Y1[o] = bf16_rne(acc[t][reg] + bt);
            }
        }
    }
}

// ---------------------------------------------------------------------------
// Flash decay attention, 4 waves/block cooperating on ONE 16-row strip,
// j-range split round-robin (wave wv takes tiles jt = wv, wv+4, ...).
// Fixed stabilizers (log2-domain scores; all exps raw v_exp_f32).
// Pass A: per-tile raw exp row-sums -> LDS table sTS.  barrier.
// Each wave derives Z and its tiles' cumsum bases from sTS.
// Pass B: barrier-free per wave (scores, DPP scan, decay, p2, PV-MFMA).
// barrier. O/Z2 LDS-reduced; output written as swizzled hi/lo concat.
// ---------------------------------------------------------------------------
#define VPAD 72

__device__ __forceinline__ void score_tile(f32x4 (&a)[4],
    const ushort_t* __restrict__ Kbh, const ushort_t* __restrict__ Kbl,
    int jt, const bf16x8& qhi, const bf16x8& qlo, int lane, int lr, int lq,
    bool domask, int i0)
{
    #pragma unroll
    for (int tt = 0; tt < 4; tt++) {
        const size_t ko = (size_t)(jt * 4 + tt) * 512 + lane * 8;
        const bf16x8 khi = *(const bf16x8*)(Kbh + ko);
        const bf16x8 klo = *(const bf16x8*)(Kbl + ko);
        f32x4 v = {0.f, 0.f, 0.f, 0.f};
        v = __builtin_amdgcn_mfma_f32_16x16x32_bf16(qlo, khi, v, 0, 0, 0);
        v = __builtin_amdgcn_mfma_f32_16x16x32_bf16(qhi, klo, v, 0, 0, 0);
        v = __builtin_amdgcn_mfma_f32_16x16x32_bf16(qhi, khi, v, 0, 0, 0);
        a[tt] = v;
    }
    if (domask) {
        #pragma unroll
        for (int tt = 0; tt < 4; tt++)
            #pragma unroll
            for (int r = 0; r < 4; r++) {
                const int irow = i0 + lq * 4 + r;
                const int j    = jt * 64 + tt * 16 + lr;
                if (j > irow) a[tt][r] = -3.0e38f;
            }
    }
}

__global__ __launch_bounds__(256)
void attn_flash(const ushort_t* __restrict__ Qh, const ushort_t* __restrict__ Ql,
                const ushort_t* __restrict__ Kh, const ushort_t* __restrict__ Kl,
                const ushort_t* __restrict__ Vs, const float* __restrict__ gammas,
                ushort_t* __restrict__ Ch, ushort_t* __restrict__ Cl)
{
    __shared__ float sTS[16][36];                    // per-row per-tile raw exp sums
    __shared__ __align__(16) ushort_t sP[4][16 * VPAD];
    __shared__ float sO[4][16][32];
    __shared__ float sZ[4][16];

    const int tid  = threadIdx.x;
    const int lane = tid & 63, wv = tid >> 6;
    const int lr   = lane & 15, lq = lane >> 4;
    const int unit = blockIdx.x >> 7;                // longest blocks first
    const int tq   = 31 - unit;
    const int sub  = blockIdx.x & 127;
    const int bh   = sub & 31;
    const int st   = sub >> 5;                       // 16-row strip in 64-row group
    const int h    = bh & 7, b = bh >> 3;
    const int i0   = tq * 64 + st * 16;

    const size_t hb = (size_t)bh * (S_ * DK_);
    const ushort_t* Kbh = Kh + hb;
    const ushort_t* Kbl = Kl + hb;
    const ushort_t* Vb  = Vs + hb;

    const float g   = gammas[h];
    const float gl2 = -((g > 20.f) ? g : log1pf(__expf(g))) * LOG2E;

    const size_t qoff = hb + (size_t)(i0 >> 4) * 512 + lane * 8;
    const bf16x8 qhi = *(const bf16x8*)(Qh + qoff);
    const bf16x8 qlo = *(const bf16x8*)(Ql + qoff);

    // ================= PASS A: per-tile raw exp row-sums ==================
    for (int jt = wv; jt <= tq; jt += 4) {
        f32x4 a[4];
        score_tile(a, Kbh, Kbl, jt, qhi, qlo, lane, lr, lq, jt == tq, i0);
        #pragma unroll
        for (int r = 0; r < 4; r++) {
            float rs = (EXP2F(a[0][r]) + EXP2F(a[1][r]))
                     + (EXP2F(a[2][r]) + EXP2F(a[3][r]));
            rs += __shfl_xor(rs, 1); rs += __shfl_xor(rs, 2);
            rs += __shfl_xor(rs, 4); rs += __shfl_xor(rs, 8);
            if (lr == 0) sTS[lq * 4 + r][jt] = rs;
        }
    }
    __syncthreads();

    // ================= PASS B (barrier-free per wave) =====================
    float z2a[4] = {0.f, 0.f, 0.f, 0.f};
    f32x4 O0 = {0.f,0.f,0.f,0.f}, O1 = {0.f,0.f,0.f,0.f};

    if (wv <= tq) {
        // Z per row (full walk) + initial base (tiles < wv)
        float invZ[4], base[4];
        #pragma unroll
        for (int r = 0; r < 4; r++) {
            const int row = lq * 4 + r;
            float run = 0.f, bs = 0.f;
            for (int t = 0; t <= tq; t++) {
                if (t < wv) bs += sTS[row][t];
                run += sTS[row][t];
            }
            invZ[r] = RCPF(run);
            base[r] = bs;
        }

        ushort_t* sPw = &sP[wv][0];
        for (int jt = wv; jt <= tq; jt += 4) {
            const int j0 = jt * 64;
            f32x4 a[4];
            score_tile(a, Kbh, Kbl, jt, qhi, qlo, lane, lr, lq, jt == tq, i0);

            // e = exp2(s'), per-16 scan, totals
            float sc[4][4], tot[4][4];
            #pragma unroll
            for (int tt = 0; tt < 4; tt++)
                #pragma unroll
                for (int r = 0; r < 4; r++) {
                    const float e = EXP2F(a[tt][r]);
                    const float s = scan16(e);
                    sc[tt][r]  = s;
                    tot[tt][r] = bcast15(s);
                }
            #pragma unroll
            for (int r = 0; r < 4; r++) {
                float run2 = base[r];
                #pragma unroll
                for (int tt = 0; tt < 4; tt++) { sc[tt][r] += run2; run2 += tot[tt][r]; }
            }
            // decay + p2 + P store
            #pragma unroll
            for (int tt = 0; tt < 4; tt++) {
                const int j = j0 + tt * 16 + lr;
                #pragma unroll
                for (int r = 0; r < 4; r++) {
                    const int irow = i0 + lq * 4 + r;
                    const float rest = fmaxf(fmaf(-sc[tt][r], invZ[r], 1.0f), 0.f);
                    const float posf = (float)(irow - j);
                    const float dist = SQRTF(fmaxf(rest * posf, 0.f));
                    const float eff  = fmaxf(EXP2F(gl2 * dist), 1e-5f);
                    const float p2   = EXP2F(a[tt][r] * eff);
                    z2a[r] += p2;
                    sPw[(lq * 4 + r) * VPAD + tt * 16 + lr] = bf16_rne(p2);
                }
            }
            // PV MFMA (wave-private LDS round trip)
            #pragma unroll
            for (int kc = 0; kc < 2; kc++) {
                const bf16x8 pa = *(const bf16x8*)&sPw[lr * VPAD + kc * 32 + lq * 8];
                const size_t vb = (size_t)(((j0 >> 5) + kc) * 2) * 512 + lane * 8;
                const bf16x8 v0 = *(const bf16x8*)(Vb + vb);
                const bf16x8 v1 = *(const bf16x8*)(Vb + vb + 512);
                O0 = __builtin_amdgcn_mfma_f32_16x16x32_bf16(pa, v0, O0, 0, 0, 0);
                O1 = __builtin_amdgcn_mfma_f32_16x16x32_bf16(pa, v1, O1, 0, 0, 0);
            }
            // advance base past tiles jt..jt+3
            if (jt + 4 <= tq) {
                #pragma unroll
                for (int r = 0; r < 4; r++) {
                    const int row = lq * 4 + r;
                    base[r] += sTS[row][jt] + sTS[row][jt+1] + sTS[row][jt+2] + sTS[row][jt+3];
                }
            }
        }
    }

    // ================= cross-wave reduce + output =========================
    #pragma unroll
    for (int r = 0; r < 4; r++) {
        float z = z2a[r];
        z += __shfl_xor(z, 1); z += __shfl_xor(z, 2);
        z += __shfl_xor(z, 4); z += __shfl_xor(z, 8);
        if (lr == 0) sZ[wv][lq * 4 + r] = z;
        sO[wv][lq * 4 + r][lr]      = O0[r];
        sO[wv][lq * 4 + r][16 + lr] = O1[r];
    }
    __syncthreads();

    #pragma unroll
    for (int p = 0; p < 2; p++) {
        const int pid = tid + p * 256;
        const int row = pid >> 5, d = pid & 31;
        const float v = (sO[0][row][d] + sO[1][row][d]) + (sO[2][row][d] + sO[3][row][d]);
        const float z = (sZ[0][row] + sZ[1][row]) + (sZ[2][row] + sZ[3][row]);
        const float y = v * RCPF(z);
        const int nIdx = b * S_ + i0 + row;
        const size_t o = ((size_t)(nIdx >> 4) * 8 + h) * 512
                       + (d >> 3) * 128 + (nIdx & 15) * 8 + (d & 7);
        const ushort_t hbb = bf16_rne(y);
        Ch[o] = hbb;
        Cl[o] = bf16_rne(y - bf16_to_f(hbb));
    }
}

// ---------------------------------------------------------------------------
extern "C" void kernel_launch(void* const* d_in, const int* in_sizes, int n_in,
                              void* d_out, int out_size, void* d_ws, size_t ws_size,
                              hipStream_t stream)
{
    const float* q      = (const float*)d_in[0];
    const float* k      = (const float*)d_in[1];
    const float* v      = (const float*)d_in[2];
    // d_in[3] = causal mask (analytic; unused)
    const float* Wq     = (const float*)d_in[4];
    const float* bq     = (const float*)d_in[5];
    const float* Wk     = (const float*)d_in[6];
    const float* bk     = (const float*)d_in[7];
    const float* Wv     = (const float*)d_in[8];
    const float* bv     = (const float*)d_in[9];
    const float* Wo     = (const float*)d_in[10];
    const float* bo     = (const float*)d_in[11];
    const float* gammas = (const float*)d_in[12];
    float* out = (float*)d_out;

    const size_t N2 = (size_t)NROWS * E_;      // 2,097,152 elements
    const size_t WN = (size_t)E_ * E_;         // 65,536

    ushort_t* p   = (ushort_t*)d_ws;
    ushort_t* xh  = p;                         // 3*N2 (inputs hi)
    ushort_t* xl  = xh + 3 * N2;               // 3*N2 (inputs lo)
    ushort_t* wh  = xl + 3 * N2;               // 4*WN
    ushort_t* wl  = wh + 4 * WN;               // 4*WN
    ushort_t* qh  = wl + 4 * WN;
    ushort_t* ql  = qh + N2;
    ushort_t* kh  = ql + N2;
    ushort_t* kl  = kh + N2;
    ushort_t* vt  = kl + N2;
    // concat aliases the (dead after projections) input-conversion region
    ushort_t* ch  = xh;
    ushort_t* cl  = xh + N2;

    conv_all<<<dim3(NROWS / 16, 7), 256, 0, stream>>>(q, k, v, Wq, Wk, Wv, Wo,
                                                      xh, xl, wh, wl);

    dim3 ggrd(E_ / 64, NROWS / 16);
    gemm_frag<<<ggrd, 64, 0, stream>>>(xh + 0*N2, xl + 0*N2, wh + 0*WN, wl + 0*WN,
                                       bq, 1, QSCALE, qh, ql, nullptr);
    gemm_frag<<<ggrd, 64, 0, stream>>>(xh + 1*N2, xl + 1*N2, wh + 1*WN, wl + 1*WN,
                                       bk, 1, 1.0f, kh, kl, nullptr);
    gemm_frag<<<ggrd, 64, 0, stream>>>(xh + 2*N2, xl + 2*N2, wh + 2*WN, wl + 2*WN,
                                       bv, 2, 1.0f, vt, nullptr, nullptr);

    attn_flash<<<32 * 32 * 4, 256, 0, stream>>>(qh, ql, kh, kl, vt, gammas, ch, cl);

    gemm_frag<<<ggrd, 64, 0, stream>>>(ch, cl, wh + 3*WN, wl + 3*WN,
                                       bo, 0, 1.0f, nullptr, nullptr, out);
}

// Round 7
// 236.174 us; speedup vs baseline: 1.6218x; 1.0338x over previous
//
#include <hip/hip_runtime.h>
#include <math.h>

#define B_   4
#define S_   2048
#define E_   256
#define H_   8
#define DK_  32
#define NROWS (B_*S_)   // 8192

typedef unsigned short ushort_t;
typedef __attribute__((ext_vector_type(8))) short  bf16x8;
typedef __attribute__((ext_vector_type(4))) float  f32x4;

#define LOG2E 1.4426950408889634f
#define QSCALE (0.17677669529663687f * 1.4426950408889634f)   // 1/sqrt(32) * log2(e)

#if __has_builtin(__builtin_amdgcn_exp2f)
#define EXP2F(x) __builtin_amdgcn_exp2f(x)
#else
#define EXP2F(x) exp2f(x)
#endif
#if __has_builtin(__builtin_amdgcn_sqrtf)
#define SQRTF(x) __builtin_amdgcn_sqrtf(x)
#else
#define SQRTF(x) sqrtf(x)
#endif
#if __has_builtin(__builtin_amdgcn_rcpf)
#define RCPF(x) __builtin_amdgcn_rcpf(x)
#else
#define RCPF(x) (1.0f/(x))
#endif

__device__ __forceinline__ ushort_t bf16_rne(float x)
{
    unsigned int u = __float_as_uint(x);
    unsigned int r = u + 0x7FFFu + ((u >> 16) & 1u);
    return (ushort_t)(r >> 16);
}
__device__ __forceinline__ float bf16_to_f(ushort_t h)
{
    return __uint_as_float(((unsigned int)h) << 16);
}

// 16-lane (DPP-row) inclusive prefix scan: 4 full-rate VALU adds.
__device__ __forceinline__ float scan16(float x)
{
    x += __int_as_float(__builtin_amdgcn_update_dpp(0, __float_as_int(x), 0x111, 0xF, 0xF, true));
    x += __int_as_float(__builtin_amdgcn_update_dpp(0, __float_as_int(x), 0x112, 0xF, 0xF, true));
    x += __int_as_float(__builtin_amdgcn_update_dpp(0, __float_as_int(x), 0x114, 0xF, 0xF, true));
    x += __int_as_float(__builtin_amdgcn_update_dpp(0, __float_as_int(x), 0x118, 0xF, 0xF, true));
    return x;
}
__device__ __forceinline__ float bcast15(float x)
{
    return __int_as_float(__builtin_amdgcn_ds_swizzle(__float_as_int(x), 0x1F0));
}

// ===========================================================================
// Fragment-swizzled layout: [rows][K] operand stored as contiguous 512-elem
// blocks (16 rows x 32 k); a wave's fragment load = base + block*512 + lane*8.
//   intra(n,k) = ((k>>3)&3)*128 + (n&15)*8 + (k&7)
// ===========================================================================

// ---------------------------------------------------------------------------
// conv: fp32 [rows][256] -> swizzled hi/lo bf16.  z<3: q,k,v; z>=3: weights.
// ---------------------------------------------------------------------------
__global__ __launch_bounds__(256)
void conv_all(const float* __restrict__ q, const float* __restrict__ k,
              const float* __restrict__ v,
              const float* __restrict__ Wq, const float* __restrict__ Wk,
              const float* __restrict__ Wv, const float* __restrict__ Wo,
              ushort_t* __restrict__ xh, ushort_t* __restrict__ xl,
              ushort_t* __restrict__ wh, ushort_t* __restrict__ wl)
{
    const int z = blockIdx.y;
    const float* src;
    ushort_t *dh, *dl;
    if (z < 3) {
        src = (z == 0) ? q : (z == 1) ? k : v;
        dh = xh + (size_t)z * (NROWS * E_);
        dl = xl + (size_t)z * (NROWS * E_);
    } else {
        if (blockIdx.x >= 16) return;
        src = (z == 3) ? Wq : (z == 4) ? Wk : (z == 5) ? Wv : Wo;
        dh = wh + (size_t)(z - 3) * (E_ * E_);
        dl = wl + (size_t)(z - 3) * (E_ * E_);
    }
    const int n0 = blockIdx.x * 16;
    const int lr = threadIdx.x & 15, kq = threadIdx.x >> 4;   // kq 0..15
    #pragma unroll
    for (int half = 0; half < 2; half++) {
        const int kk = kq * 8 + half * 128;
        const float* s = src + (size_t)(n0 + lr) * E_ + kk;
        const float4 a = *(const float4*)s;
        const float4 b = *(const float4*)(s + 4);
        const float xs[8] = {a.x, a.y, a.z, a.w, b.x, b.y, b.z, b.w};
        bf16x8 hv, lv;
        #pragma unroll
        for (int e = 0; e < 8; e++) {
            const ushort_t hb = bf16_rne(xs[e]);
            hv[e] = (short)hb;
            lv[e] = (short)bf16_rne(xs[e] - bf16_to_f(hb));
        }
        const size_t o = ((size_t)blockIdx.x * 8 + (kk >> 5)) * 512
                       + ((kk >> 3) & 3) * 128 + lr * 8;
        *(bf16x8*)&dh[o] = hv;
        *(bf16x8*)&dl[o] = lv;
    }
}

// ---------------------------------------------------------------------------
// Shared MFMA core: 16 n-rows x 64 m-cols, K=256, register double-buffered
// K-loop (loads for chunk kc+1 issued before MFMAs of chunk kc).
// ---------------------------------------------------------------------------
__device__ __forceinline__ void gemm_core(
    const ushort_t* __restrict__ Ah, const ushort_t* __restrict__ Al,
    const ushort_t* __restrict__ Bh, const ushort_t* __restrict__ Bl,
    size_t abase, size_t wbase, f32x4 (&acc)[4])
{
    bf16x8 aH = *(const bf16x8*)(Ah + abase);
    bf16x8 aL = *(const bf16x8*)(Al + abase);
    bf16x8 bH[4], bL[4];
    #pragma unroll
    for (int t = 0; t < 4; t++) {
        bH[t] = *(const bf16x8*)(Bh + wbase + (size_t)t * 8 * 512);
        bL[t] = *(const bf16x8*)(Bl + wbase + (size_t)t * 8 * 512);
    }
    #pragma unroll
    for (int kc = 0; kc < 8; kc++) {
        const int kn = (kc + 1) & 7;              // wraps; kc=7 prefetch unused
        bf16x8 aH2 = *(const bf16x8*)(Ah + abase + (size_t)kn * 512);
        bf16x8 aL2 = *(const bf16x8*)(Al + abase + (size_t)kn * 512);
        bf16x8 bH2[4], bL2[4];
        #pragma unroll
        for (int t = 0; t < 4; t++) {
            bH2[t] = *(const bf16x8*)(Bh + wbase + (size_t)(t * 8 + kn) * 512);
            bL2[t] = *(const bf16x8*)(Bl + wbase + (size_t)(t * 8 + kn) * 512);
        }
        #pragma unroll
        for (int t = 0; t < 4; t++) {
            acc[t] = __builtin_amdgcn_mfma_f32_16x16x32_bf16(aL, bH[t], acc[t], 0, 0, 0);
            acc[t] = __builtin_amdgcn_mfma_f32_16x16x32_bf16(aH, bL[t], acc[t], 0, 0, 0);
            acc[t] = __builtin_amdgcn_mfma_f32_16x16x32_bf16(aH, bH[t], acc[t], 0, 0, 0);
        }
        aH = aH2; aL = aL2;
        #pragma unroll
        for (int t = 0; t < 4; t++) { bH[t] = bH2[t]; bL[t] = bL2[t]; }
    }
}

// ---------------------------------------------------------------------------
// Fused Q/K/V projections. Block = 4 waves = 4 n-strips sharing one m-block.
// z=0: Q -> attn layout hi/lo scaled; z=1: K -> hi/lo; z=2: V -> B-frag bf16.
// ---------------------------------------------------------------------------
__global__ __launch_bounds__(256)
void gemm_qkv(const ushort_t* __restrict__ Xh, const ushort_t* __restrict__ Xl,
              const ushort_t* __restrict__ Wh, const ushort_t* __restrict__ Wl,
              const float* __restrict__ bqp, const float* __restrict__ bkp,
              const float* __restrict__ bvp,
              ushort_t* __restrict__ Qh, ushort_t* __restrict__ Ql,
              ushort_t* __restrict__ Kh, ushort_t* __restrict__ Kl,
              ushort_t* __restrict__ Vt)
{
    const size_t N2 = (size_t)NROWS * E_;
    const size_t WN = (size_t)E_ * E_;
    const int z = blockIdx.z;
    const ushort_t* Ah = Xh + (size_t)z * N2;
    const ushort_t* Al = Xl + (size_t)z * N2;
    const ushort_t* Bh = Wh + (size_t)z * WN;
    const ushort_t* Bl = Wl + (size_t)z * WN;
    const float* bias = (z == 0) ? bqp : (z == 1) ? bkp : bvp;
    const float scale = (z == 0) ? QSCALE : 1.0f;

    const int lane = threadIdx.x & 63, wv = threadIdx.x >> 6;
    const int lr = lane & 15, lq = lane >> 4;
    const int mb = blockIdx.x;
    const int nstrip = blockIdx.y * 4 + wv;
    const size_t abase = (size_t)nstrip * 4096 + lane * 8;
    const size_t wbase = (size_t)mb * (4 * 8 * 512) + lane * 8;

    f32x4 acc[4] = {{0,0,0,0},{0,0,0,0},{0,0,0,0},{0,0,0,0}};
    gemm_core(Ah, Al, Bh, Bl, abase, wbase, acc);

    #pragma unroll
    for (int t = 0; t < 4; t++) {
        const int col = mb * 64 + t * 16 + lr;
        const float bt = bias[col];
        const int h = col >> 5, d = col & 31;
        if (z <= 1) {                           // Q/K -> attn frag layout hi/lo
            ushort_t* Y1 = (z == 0) ? Qh : Kh;
            ushort_t* Y2 = (z == 0) ? Ql : Kl;
            #pragma unroll
            for (int reg = 0; reg < 4; reg++) {
                const int n  = nstrip * 16 + lq * 4 + reg;
                const int bI = n >> 11, sI = n & (S_ - 1);
                const size_t o = (size_t)(bI * H_ + h) * (S_ * DK_)
                               + (size_t)(sI >> 4) * 512
                               + ((d >> 3) & 3) * 128 + (sI & 15) * 8 + (d & 7);
                const float y = (acc[t][reg] + bt) * scale;
                const ushort_t hb = bf16_rne(y);
                Y1[o] = hb;
                Y2[o] = bf16_rne(y - bf16_to_f(hb));
            }
        } else {                                // V -> attn B-frag layout
            #pragma unroll
            for (int reg = 0; reg < 4; reg++) {
                const int n  = nstrip * 16 + lq * 4 + reg;
                const int bI = n >> 11, sI = n & (S_ - 1);
                const size_t o = (size_t)(bI * H_ + h) * (S_ * DK_)
                               + (size_t)((sI >> 5) * 2 + (d >> 4)) * 512
                               + ((sI >> 3) & 3) * 128 + (d & 15) * 8 + (sI & 7);
                Vt[o] = bf16_rne(acc[t][reg] + bt);
            }
        }
    }
}

// ---------------------------------------------------------------------------
// Output projection: fp32 out [n][E].
// ---------------------------------------------------------------------------
__global__ __launch_bounds__(256)
void gemm_out(const ushort_t* __restrict__ Xh, const ushort_t* __restrict__ Xl,
              const ushort_t* __restrict__ Wh, const ushort_t* __restrict__ Wl,
              const float* __restrict__ bias, float* __restrict__ Yf)
{
    const int lane = threadIdx.x & 63, wv = threadIdx.x >> 6;
    const int lr = lane & 15, lq = lane >> 4;
    const int mb = blockIdx.x;
    const int nstrip = blockIdx.y * 4 + wv;
    const size_t abase = (size_t)nstrip * 4096 + lane * 8;
    const size_t wbase = (size_t)mb * (4 * 8 * 512) + lane * 8;

    f32x4 acc[4] = {{0,0,0,0},{0,0,0,0},{0,0,0,0},{0,0,0,0}};
    gemm_core(Xh, Xl, Wh, Wl, abase, wbase, acc);

    #pragma unroll
    for (int t = 0; t < 4; t++) {
        const int col = mb * 64 + t * 16 + lr;
        const float bt = bias[col];
        #pragma unroll
        for (int reg = 0; reg < 4; reg++) {
            const int n = nstrip * 16 + lq * 4 + reg;
            Yf[(size_t)n * E_ + col] = acc[t][reg] + bt;
        }
    }
}

// ---------------------------------------------------------------------------
// Flash decay attention (unchanged from round 6).
// ---------------------------------------------------------------------------
#define VPAD 72

__device__ __forceinline__ void score_tile(f32x4 (&a)[4],
    const ushort_t* __restrict__ Kbh, const ushort_t* __restrict__ Kbl,
    int jt, const bf16x8& qhi, const bf16x8& qlo, int lane, int lr, int lq,
    bool domask, int i0)
{
    #pragma unroll
    for (int tt = 0; tt < 4; tt++) {
        const size_t ko = (size_t)(jt * 4 + tt) * 512 + lane * 8;
        const bf16x8 khi = *(const bf16x8*)(Kbh + ko);
        const bf16x8 klo = *(const bf16x8*)(Kbl + ko);
        f32x4 v = {0.f, 0.f, 0.f, 0.f};
        v = __builtin_amdgcn_mfma_f32_16x16x32_bf16(qlo, khi, v, 0, 0, 0);
        v = __builtin_amdgcn_mfma_f32_16x16x32_bf16(qhi, klo, v, 0, 0, 0);
        v = __builtin_amdgcn_mfma_f32_16x16x32_bf16(qhi, khi, v, 0, 0, 0);
        a[tt] = v;
    }
    if (domask) {
        #pragma unroll
        for (int tt = 0; tt < 4; tt++)
            #pragma unroll
            for (int r = 0; r < 4; r++) {
                const int irow = i0 + lq * 4 + r;
                const int j    = jt * 64 + tt * 16 + lr;
                if (j > irow) a[tt][r] = -3.0e38f;
            }
    }
}

__global__ __launch_bounds__(256)
void attn_flash(const ushort_t* __restrict__ Qh, const ushort_t* __restrict__ Ql,
                const ushort_t* __restrict__ Kh, const ushort_t* __restrict__ Kl,
                const ushort_t* __restrict__ Vs, const float* __restrict__ gammas,
                ushort_t* __restrict__ Ch, ushort_t* __restrict__ Cl)
{
    __shared__ float sTS[16][36];
    __shared__ __align__(16) ushort_t sP[4][16 * VPAD];
    __shared__ float sO[4][16][32];
    __shared__ float sZ[4][16];

    const int tid  = threadIdx.x;
    const int lane = tid & 63, wv = tid >> 6;
    const int lr   = lane & 15, lq = lane >> 4;
    const int unit = blockIdx.x >> 7;
    const int tq   = 31 - unit;
    const int sub  = blockIdx.x & 127;
    const int bh   = sub & 31;
    const int st   = sub >> 5;
    const int h    = bh & 7, b = bh >> 3;
    const int i0   = tq * 64 + st * 16;

    const size_t hb = (size_t)bh * (S_ * DK_);
    const ushort_t* Kbh = Kh + hb;
    const ushort_t* Kbl = Kl + hb;
    const ushort_t* Vb  = Vs + hb;

    const float g   = gammas[h];
    const float gl2 = -((g > 20.f) ? g : log1pf(__expf(g))) * LOG2E;

    const size_t qoff = hb + (size_t)(i0 >> 4) * 512 + lane * 8;
    const bf16x8 qhi = *(const bf16x8*)(Qh + qoff);
    const bf16x8 qlo = *(const bf16x8*)(Ql + qoff);

    // ================= PASS A: per-tile raw exp row-sums ==================
    for (int jt = wv; jt <= tq; jt += 4) {
        f32x4 a[4];
        score_tile(a, Kbh, Kbl, jt, qhi, qlo, lane, lr, lq, jt == tq, i0);
        #pragma unroll
        for (int r = 0; r < 4; r++) {
            float rs = (EXP2F(a[0][r]) + EXP2F(a[1][r]))
                     + (EXP2F(a[2][r]) + EXP2F(a[3][r]));
            rs += __shfl_xor(rs, 1); rs += __shfl_xor(rs, 2);
            rs += __shfl_xor(rs, 4); rs += __shfl_xor(rs, 8);
            if (lr == 0) sTS[lq * 4 + r][jt] = rs;
        }
    }
    __syncthreads();

    // ================= PASS B (barrier-free per wave) =====================
    float z2a[4] = {0.f, 0.f, 0.f, 0.f};
    f32x4 O0 = {0.f,0.f,0.f,0.f}, O1 = {0.f,0.f,0.f,0.f};

    if (wv <= tq) {
        float invZ[4], base[4];
        #pragma unroll
        for (int r = 0; r < 4; r++) {
            const int row = lq * 4 + r;
            float run = 0.f, bs = 0.f;
            for (int t = 0; t <= tq; t++) {
                if (t < wv) bs += sTS[row][t];
                run += sTS[row][t];
            }
            invZ[r] = RCPF(run);
            base[r] = bs;
        }

        ushort_t* sPw = &sP[wv][0];
        for (int jt = wv; jt <= tq; jt += 4) {
            const int j0 = jt * 64;
            f32x4 a[4];
            score_tile(a, Kbh, Kbl, jt, qhi, qlo, lane, lr, lq, jt == tq, i0);

            float sc[4][4], tot[4][4];
            #pragma unroll
            for (int tt = 0; tt < 4; tt++)
                #pragma unroll
                for (int r = 0; r < 4; r++) {
                    const float e = EXP2F(a[tt][r]);
                    const float s = scan16(e);
                    sc[tt][r]  = s;
                    tot[tt][r] = bcast15(s);
                }
            #pragma unroll
            for (int r = 0; r < 4; r++) {
                float run2 = base[r];
                #pragma unroll
                for (int tt = 0; tt < 4; tt++) { sc[tt][r] += run2; run2 += tot[tt][r]; }
            }
            #pragma unroll
            for (int tt = 0; tt < 4; tt++) {
                const int j = j0 + tt * 16 + lr;
                #pragma unroll
                for (int r = 0; r < 4; r++) {
                    const int irow = i0 + lq * 4 + r;
                    const float rest = fmaxf(fmaf(-sc[tt][r], invZ[r], 1.0f), 0.f);
                    const float posf = (float)(irow - j);
                    const float dist = SQRTF(fmaxf(rest * posf, 0.f));
                    const float eff  = fmaxf(EXP2F(gl2 * dist), 1e-5f);
                    const float p2   = EXP2F(a[tt][r] * eff);
                    z2a[r] += p2;
                    sPw[(lq * 4 + r) * VPAD + tt * 16 + lr] = bf16_rne(p2);
                }
            }
            #pragma unroll
            for (int kc = 0; kc < 2; kc++) {
                const bf16x8 pa = *(const bf16x8*)&sPw[lr * VPAD + kc * 32 + lq * 8];
                const size_t vb = (size_t)(((j0 >> 5) + kc) * 2) * 512 + lane * 8;
                const bf16x8 v0 = *(const bf16x8*)(Vb + vb);
                const bf16x8 v1 = *(const bf16x8*)(Vb + vb + 512);
                O0 = __builtin_amdgcn_mfma_f32_16x16x32_bf16(pa, v0, O0, 0, 0, 0);
                O1 = __builtin_amdgcn_mfma_f32_16x16x32_bf16(pa, v1, O1, 0, 0, 0);
            }
            if (jt + 4 <= tq) {
                #pragma unroll
                for (int r = 0; r < 4; r++) {
                    const int row = lq * 4 + r;
                    base[r] += sTS[row][jt] + sTS[row][jt+1] + sTS[row][jt+2] + sTS[row][jt+3];
                }
            }
        }
    }

    // ================= cross-wave reduce + output =========================
    #pragma unroll
    for (int r = 0; r < 4; r++) {
        float z = z2a[r];
        z += __shfl_xor(z, 1); z += __shfl_xor(z, 2);
        z += __shfl_xor(z, 4); z += __shfl_xor(z, 8);
        if (lr == 0) sZ[wv][lq * 4 + r] = z;
        sO[wv][lq * 4 + r][lr]      = O0[r];
        sO[wv][lq * 4 + r][16 + lr] = O1[r];
    }
    __syncthreads();

    #pragma unroll
    for (int p = 0; p < 2; p++) {
        const int pid = tid + p * 256;
        const int row = pid >> 5, d = pid & 31;
        const float v = (sO[0][row][d] + sO[1][row][d]) + (sO[2][row][d] + sO[3][row][d]);
        const float z = (sZ[0][row] + sZ[1][row]) + (sZ[2][row] + sZ[3][row]);
        const float y = v * RCPF(z);
        const int nIdx = b * S_ + i0 + row;
        const size_t o = ((size_t)(nIdx >> 4) * 8 + h) * 512
                       + (d >> 3) * 128 + (nIdx & 15) * 8 + (d & 7);
        const ushort_t hbb = bf16_rne(y);
        Ch[o] = hbb;
        Cl[o] = bf16_rne(y - bf16_to_f(hbb));
    }
}

// ---------------------------------------------------------------------------
extern "C" void kernel_launch(void* const* d_in, const int* in_sizes, int n_in,
                              void* d_out, int out_size, void* d_ws, size_t ws_size,
                              hipStream_t stream)
{
    const float* q      = (const float*)d_in[0];
    const float* k      = (const float*)d_in[1];
    const float* v      = (const float*)d_in[2];
    // d_in[3] = causal mask (analytic; unused)
    const float* Wq     = (const float*)d_in[4];
    const float* bq     = (const float*)d_in[5];
    const float* Wk     = (const float*)d_in[6];
    const float* bk     = (const float*)d_in[7];
    const float* Wv     = (const float*)d_in[8];
    const float* bv     = (const float*)d_in[9];
    const float* Wo     = (const float*)d_in[10];
    const float* bo     = (const float*)d_in[11];
    const float* gammas = (const float*)d_in[12];
    float* out = (float*)d_out;

    const size_t N2 = (size_t)NROWS * E_;      // 2,097,152 elements
    const size_t WN = (size_t)E_ * E_;         // 65,536

    ushort_t* p   = (ushort_t*)d_ws;
    ushort_t* xh  = p;                         // 3*N2 (inputs hi)
    ushort_t* xl  = xh + 3 * N2;               // 3*N2 (inputs lo)
    ushort_t* wh  = xl + 3 * N2;               // 4*WN
    ushort_t* wl  = wh + 4 * WN;               // 4*WN
    ushort_t* qh  = wl + 4 * WN;
    ushort_t* ql  = qh + N2;
    ushort_t* kh  = ql + N2;
    ushort_t* kl  = kh + N2;
    ushort_t* vt  = kl + N2;
    // concat aliases the (dead after projections) input-conversion region
    ushort_t* ch  = xh;
    ushort_t* cl  = xh + N2;

    conv_all<<<dim3(NROWS / 16, 7), 256, 0, stream>>>(q, k, v, Wq, Wk, Wv, Wo,
                                                      xh, xl, wh, wl);

    gemm_qkv<<<dim3(E_ / 64, NROWS / 64, 3), 256, 0, stream>>>(
        xh, xl, wh, wl, bq, bk, bv, qh, ql, kh, kl, vt);

    attn_flash<<<32 * 32 * 4, 256, 0, stream>>>(qh, ql, kh, kl, vt, gammas, ch, cl);

    gemm_out<<<dim3(E_ / 64, NROWS / 64), 256, 0, stream>>>(
        ch, cl, wh + 3 * WN, wl + 3 * WN, bo, out);
}